// Round 4
// baseline (368.307 us; speedup 1.0000x reference)
//
#include <hip/hip_runtime.h>
#include <hip/hip_fp16.h>

// K-Planes feature field: N=1M points, C=32 channels, 3 pairs, 3 resolutions.
// out[n, r*32 + c] = prod_p bilinear(plane[r][p][c], coords_p(n))
//
// R3 strategy:
//  - fp16 channel-last planes in d_ws (corner gather = contiguous segments)
//  - Morton-cell counting sort of points -> gathers are L2 hits
//  - sampler: 4 lanes/point, 8 ch/lane, 16B loads, packed __half2 interp
//    (halves thread count + address math + interp ops vs R2)

constexpr int kN = 1048576;
constexpr int kC = 32;
constexpr int kCells = 32 * 32 * 32;   // 15-bit Morton key

typedef float f32x4 __attribute__((ext_vector_type(4)));
typedef short s16x8 __attribute__((ext_vector_type(8)));

// ---- transpose+convert (3, C, R, R) fp32 -> (3, R, R, C) fp16 ----
__global__ __launch_bounds__(1024) void kp_transpose_h(const float* __restrict__ in,
                                                       __half* __restrict__ out, int R) {
    __shared__ float tile[32][33];
    const int tx = threadIdx.x, ty = threadIdx.y;
    const int x0 = blockIdx.x * 32;
    const int y  = blockIdx.y;
    const int p  = blockIdx.z;
    tile[ty][tx] = in[(((size_t)p * kC + ty) * R + y) * R + x0 + tx];
    __syncthreads();
    out[(((size_t)p * R + y) * R + x0 + ty) * kC + tx] = __float2half_rn(tile[tx][ty]);
}

// ---- Morton cell key from coords in [-1,1] ----
__device__ __forceinline__ unsigned cell_key(float x, float y, float z) {
    int cx = min(max((int)((x + 1.f) * 16.f), 0), 31);
    int cy = min(max((int)((y + 1.f) * 16.f), 0), 31);
    int cz = min(max((int)((z + 1.f) * 16.f), 0), 31);
    unsigned m = 0;
#pragma unroll
    for (int b = 0; b < 5; ++b) {
        m |= ((unsigned)((cx >> b) & 1)) << (3 * b);
        m |= ((unsigned)((cy >> b) & 1)) << (3 * b + 1);
        m |= ((unsigned)((cz >> b) & 1)) << (3 * b + 2);
    }
    return m;
}

__global__ __launch_bounds__(256) void kp_zero(unsigned* __restrict__ p, int n) {
    int i = blockIdx.x * 256 + threadIdx.x;
    if (i < n) p[i] = 0u;
}

__global__ __launch_bounds__(256) void kp_hist(const float* __restrict__ xs,
                                               unsigned* __restrict__ hist) {
    int n = blockIdx.x * 256 + threadIdx.x;
    float x = xs[n * 3 + 0], y = xs[n * 3 + 1], z = xs[n * 3 + 2];
    atomicAdd(&hist[cell_key(x, y, z)], 1u);
}

// single-block exclusive scan of kCells entries -> cursor
__global__ __launch_bounds__(1024) void kp_scan(const unsigned* __restrict__ hist,
                                                unsigned* __restrict__ cursor) {
    __shared__ unsigned sums[1024];
    const int t = threadIdx.x;
    const int per = kCells / 1024;          // 32
    unsigned local[32];
    unsigned s = 0;
    const int base = t * per;
#pragma unroll
    for (int i = 0; i < per; ++i) { local[i] = hist[base + i]; s += local[i]; }
    sums[t] = s;
    __syncthreads();
    for (int off = 1; off < 1024; off <<= 1) {
        unsigned v = (t >= off) ? sums[t - off] : 0u;
        __syncthreads();
        sums[t] += v;
        __syncthreads();
    }
    unsigned run = (t == 0) ? 0u : sums[t - 1];   // exclusive prefix
#pragma unroll
    for (int i = 0; i < per; ++i) { cursor[base + i] = run; run += local[i]; }
}

__global__ __launch_bounds__(256) void kp_scatter(const float* __restrict__ xs,
                                                  unsigned* __restrict__ cursor,
                                                  f32x4* __restrict__ sorted) {
    int n = blockIdx.x * 256 + threadIdx.x;
    float x = xs[n * 3 + 0], y = xs[n * 3 + 1], z = xs[n * 3 + 2];
    unsigned pos = atomicAdd(&cursor[cell_key(x, y, z)], 1u);
    f32x4 v = {x, y, z, __uint_as_float((unsigned)n)};
    __builtin_nontemporal_store(v, &sorted[pos]);
}

// ---- packed fp16 bilinear: 8 channels/lane, running product across pairs ----
template<int R>
__device__ __forceinline__ void sample_res_pk(const __half* __restrict__ planes, int c8,
                                              const float* gx, const float* gy,
                                              __half2 prod[4]) {
    const float fr = (float)(R - 1);
    prod[0] = prod[1] = prod[2] = prod[3] = __float2half2_rn(1.f);
#pragma unroll
    for (int p = 0; p < 3; ++p) {
        float ix = (gx[p] + 1.f) * 0.5f * fr;
        float iy = (gy[p] + 1.f) * 0.5f * fr;
        float x0f = fminf(fmaxf(floorf(ix), 0.f), fr);
        float y0f = fminf(fmaxf(floorf(iy), 0.f), fr);
        float wx = ix - x0f, wy = iy - y0f;
        int xi0 = (int)x0f, yi0 = (int)y0f;
        int xi1 = min(xi0 + 1, R - 1), yi1 = min(yi0 + 1, R - 1);
        const __half* pl = planes + (size_t)p * R * R * kC + c8;
        union U { s16x8 s; __half2 h[4]; } v00, v01, v10, v11;
        v00.s = *reinterpret_cast<const s16x8*>(pl + (yi0 * R + xi0) * kC);
        v01.s = *reinterpret_cast<const s16x8*>(pl + (yi0 * R + xi1) * kC);
        v10.s = *reinterpret_cast<const s16x8*>(pl + (yi1 * R + xi0) * kC);
        v11.s = *reinterpret_cast<const s16x8*>(pl + (yi1 * R + xi1) * kC);
        __half2 w00 = __float2half2_rn((1.f - wx) * (1.f - wy));
        __half2 w01 = __float2half2_rn(wx * (1.f - wy));
        __half2 w10 = __float2half2_rn((1.f - wx) * wy);
        __half2 w11 = __float2half2_rn(wx * wy);
#pragma unroll
        for (int j = 0; j < 4; ++j) {
            __half2 acc = __hmul2(v00.h[j], w00);
            acc = __hfma2(v01.h[j], w01, acc);
            acc = __hfma2(v10.h[j], w10, acc);
            acc = __hfma2(v11.h[j], w11, acc);
            prod[j] = __hmul2(prod[j], acc);
        }
    }
}

__device__ __forceinline__ void store_prod(float* __restrict__ o, const __half2 prod[4]) {
    float2 f0 = __half22float2(prod[0]);
    float2 f1 = __half22float2(prod[1]);
    float2 f2 = __half22float2(prod[2]);
    float2 f3 = __half22float2(prod[3]);
    __builtin_nontemporal_store(f32x4{f0.x, f0.y, f1.x, f1.y}, (f32x4*)o);
    __builtin_nontemporal_store(f32x4{f2.x, f2.y, f3.x, f3.y}, (f32x4*)(o + 4));
}

// ---- fused sampler over sorted points: 4 lanes/point, 8 ch/lane ----
__global__ __launch_bounds__(256) void kp_sample_sorted(const f32x4* __restrict__ pts,
                                                        const __half* __restrict__ t128,
                                                        const __half* __restrict__ t256,
                                                        const __half* __restrict__ t512,
                                                        float* __restrict__ out) {
    const int nwg = (kN * 4) / 256;                 // 16384, %8 == 0
    int bid = blockIdx.x;
    bid = (bid & 7) * (nwg / 8) + (bid >> 3);       // XCD-contiguous chunks
    const int li = threadIdx.x;
    const int n  = bid * 64 + (li >> 2);            // sorted point index
    const int c8 = (li & 3) << 3;
    f32x4 pt = pts[n];
    const float a = pt.x, b = pt.y, d = pt.z;
    const unsigned oi = __float_as_uint(pt.w);
    // PAIRS = (0,1),(0,2),(1,2); coords last dim = (gx, gy)
    const float gx[3] = {a, a, b};
    const float gy[3] = {b, d, d};
    float* o = out + (size_t)oi * 96 + c8;
    __half2 prod[4];
    sample_res_pk<128>(t128, c8, gx, gy, prod);
    store_prod(o, prod);
    sample_res_pk<256>(t256, c8, gx, gy, prod);
    store_prod(o + 32, prod);
    sample_res_pk<512>(t512, c8, gx, gy, prod);
    store_prod(o + 64, prod);
}

// ---- fallback: unsorted per-point sampler (planes-only ws) ----
template<int R>
__global__ __launch_bounds__(256) void kp_sample_h(const float* __restrict__ xs,
                                                   const __half* __restrict__ planes,
                                                   float* __restrict__ out, int rbase) {
    const int t = blockIdx.x * 256 + (int)threadIdx.x;
    const int n  = t >> 2;
    const int c8 = (t & 3) << 3;
    const float a = xs[n * 3 + 0], b = xs[n * 3 + 1], d = xs[n * 3 + 2];
    const float gx[3] = {a, a, b};
    const float gy[3] = {b, d, d};
    __half2 prod[4];
    sample_res_pk<R>(planes, c8, gx, gy, prod);
    store_prod(out + (size_t)n * 96 + rbase + c8, prod);
}

// ---- fp32 direct fallback (no ws) ----
__global__ __launch_bounds__(256) void kp_sample_f32(const float* __restrict__ xs,
                                                     const float* __restrict__ p128,
                                                     const float* __restrict__ p256,
                                                     const float* __restrict__ p512,
                                                     float* __restrict__ out) {
    const int t = blockIdx.x * 256 + (int)threadIdx.x;
    const int n = t >> 5;
    const int c = t & 31;
    const float a = xs[n * 3 + 0], b = xs[n * 3 + 1], d = xs[n * 3 + 2];
    const float gxs[3] = {a, a, b};
    const float gys[3] = {b, d, d};
    const float* planes[3] = {p128, p256, p512};
    const int Rs[3] = {128, 256, 512};
    float* o = out + (size_t)n * 96;
#pragma unroll
    for (int r = 0; r < 3; ++r) {
        const int R = Rs[r];
        const float fr = (float)(R - 1);
        float f = 1.0f;
#pragma unroll
        for (int p = 0; p < 3; ++p) {
            float ix = (gxs[p] + 1.f) * 0.5f * fr;
            float iy = (gys[p] + 1.f) * 0.5f * fr;
            float x0f = fminf(fmaxf(floorf(ix), 0.f), fr);
            float y0f = fminf(fmaxf(floorf(iy), 0.f), fr);
            float wx = ix - x0f, wy = iy - y0f;
            int xi0 = (int)x0f, yi0 = (int)y0f;
            int xi1 = min(xi0 + 1, R - 1), yi1 = min(yi0 + 1, R - 1);
            const float* pc = planes[r] + ((size_t)p * kC + c) * R * R;
            float v00 = pc[yi0 * R + xi0], v01 = pc[yi0 * R + xi1];
            float v10 = pc[yi1 * R + xi0], v11 = pc[yi1 * R + xi1];
            f *= v00 * (1.f - wx) * (1.f - wy) + v01 * wx * (1.f - wy)
               + v10 * (1.f - wx) * wy + v11 * wx * wy;
        }
        __builtin_nontemporal_store(f, o + r * 32 + c);
    }
}

extern "C" void kernel_launch(void* const* d_in, const int* in_sizes, int n_in,
                              void* d_out, int out_size, void* d_ws, size_t ws_size,
                              hipStream_t stream) {
    const float* xs   = (const float*)d_in[0];
    const float* p128 = (const float*)d_in[1];
    const float* p256 = (const float*)d_in[2];
    const float* p512 = (const float*)d_in[3];
    float* out = (float*)d_out;

    const size_t n128 = (size_t)3 * 128 * 128 * kC;
    const size_t n256 = (size_t)3 * 256 * 256 * kC;
    const size_t n512 = (size_t)3 * 512 * 512 * kC;
    const size_t planes_b = (n128 + n256 + n512) * sizeof(__half);
    const size_t sorted_b = (size_t)kN * 16;
    const size_t hist_b   = (size_t)kCells * 4;
    const size_t need_sorted = sorted_b + planes_b + 2 * hist_b + 256;
    const size_t need_plain  = planes_b;

    dim3 tblk(32, 32);
    const int nblk4 = (kN * 4) / 256;   // 16384

    if (ws_size >= need_sorted) {
        // ws layout: sorted (16B-aligned) | planes fp16 | hist | cursor
        f32x4* sorted = (f32x4*)d_ws;
        __half* t128 = (__half*)((char*)d_ws + sorted_b);
        __half* t256 = t128 + n128;
        __half* t512 = t256 + n256;
        unsigned* hist   = (unsigned*)((char*)d_ws + sorted_b + planes_b);
        unsigned* cursor = hist + kCells;

        kp_transpose_h<<<dim3(128 / 32, 128, 3), tblk, 0, stream>>>(p128, t128, 128);
        kp_transpose_h<<<dim3(256 / 32, 256, 3), tblk, 0, stream>>>(p256, t256, 256);
        kp_transpose_h<<<dim3(512 / 32, 512, 3), tblk, 0, stream>>>(p512, t512, 512);
        kp_zero<<<(kCells + 255) / 256, 256, 0, stream>>>(hist, kCells);
        kp_hist<<<kN / 256, 256, 0, stream>>>(xs, hist);
        kp_scan<<<1, 1024, 0, stream>>>(hist, cursor);
        kp_scatter<<<kN / 256, 256, 0, stream>>>(xs, cursor, sorted);
        kp_sample_sorted<<<nblk4, 256, 0, stream>>>(sorted, t128, t256, t512, out);
    } else if (ws_size >= need_plain) {
        __half* t128 = (__half*)d_ws;
        __half* t256 = t128 + n128;
        __half* t512 = t256 + n256;
        kp_transpose_h<<<dim3(128 / 32, 128, 3), tblk, 0, stream>>>(p128, t128, 128);
        kp_transpose_h<<<dim3(256 / 32, 256, 3), tblk, 0, stream>>>(p256, t256, 256);
        kp_transpose_h<<<dim3(512 / 32, 512, 3), tblk, 0, stream>>>(p512, t512, 512);
        kp_sample_h<128><<<nblk4, 256, 0, stream>>>(xs, t128, out, 0);
        kp_sample_h<256><<<nblk4, 256, 0, stream>>>(xs, t256, out, 32);
        kp_sample_h<512><<<nblk4, 256, 0, stream>>>(xs, t512, out, 64);
    } else {
        kp_sample_f32<<<(kN * 32) / 256, 256, 0, stream>>>(xs, p128, p256, p512, out);
    }
}